// Round 8
// baseline (190.768 us; speedup 1.0000x reference)
//
#include <hip/hip_runtime.h>

#define N_NODES 50000
#define N_EDGES 800000
#define IN_C    128
#define HID_C   128
#define OUT_C   64
#define NPAD    50048                       // nodes padded to 64
#define DCAP    64                          // fixed csr slots per node (mean deg 16)
#define NBIN    1564                        // 32-node bins: NPAD/32
#define EPB     2048                        // edges per scatter block
#define EBLKS   ((N_EDGES + EPB - 1) / EPB) // 391
#define PACK_BLKS 192
#define ZERO_BLKS 8
#define MM1_BLKS  ((N_NODES + 63) / 64)     // 782
#define HS_STRIDE 136                       // 128 ushorts + 8 pad -> 272B rows

typedef unsigned short ushort_t;
typedef unsigned int   uint_t;
typedef unsigned char  uchar_t;
typedef __attribute__((ext_vector_type(8))) short bf16x8;
typedef __attribute__((ext_vector_type(4))) float f32x4;
typedef __attribute__((ext_vector_type(2))) float f32x2;

__device__ inline ushort_t f2bf(float f) {
    uint_t u = __float_as_uint(f);
    uint_t r = (u + 0x7fffu + ((u >> 16) & 1u)) >> 16;
    return (ushort_t)r;
}
__device__ inline float bflo(uint_t v) { return __uint_as_float(v << 16); }
__device__ inline float bfhi(uint_t v) { return __uint_as_float(v & 0xffff0000u); }
__device__ inline uchar_t f2fp8(float v) {
    return (uchar_t)(__builtin_amdgcn_cvt_pk_fp8_f32(v, v, 0, false) & 0xff);
}
// decode one dword = 4 fp8 -> acc[0..3]
__device__ inline void acc_fp8x4(float* a, uint_t d) {
    const f32x2 lo = __builtin_amdgcn_cvt_pk_f32_fp8((int)d, false);
    const f32x2 hi = __builtin_amdgcn_cvt_pk_f32_fp8((int)d, true);
    a[0] += lo.x; a[1] += lo.y; a[2] += hi.x; a[3] += hi.y;
}
__device__ inline void acc_uint4(float* a, const uint4 v) {
    acc_fp8x4(a + 0,  v.x);
    acc_fp8x4(a + 4,  v.y);
    acc_fp8x4(a + 8,  v.z);
    acc_fp8x4(a + 12, v.w);
}

// ---------------------------------------------------------------------------
// Weight pre-pack into B-fragment order for mfma_f32_16x16x32_bf16.
// ---------------------------------------------------------------------------
__device__ inline void pack_one(const float* W, ushort_t* Wp, int K, int N, int idx) {
    const int j  = idx & 7;
    const int L  = (idx >> 3) & 63;
    const int t  = idx >> 9;
    const int KT = K / 32;
    const int kt = t % KT;
    const int ct = t / KT;
    const int k  = kt * 32 + (L >> 4) * 8 + j;
    const int n  = ct * 16 + (L & 15);
    Wp[idx] = f2bf(W[k * N + n]);
}

// ---------------------------------------------------------------------------
// K0: pack weights (blocks 0..191) | zero cnt (blocks 192..199).
// ---------------------------------------------------------------------------
__global__ __launch_bounds__(256) void k0_kernel(
    const float* __restrict__ W1l, const float* __restrict__ W1r,
    const float* __restrict__ W2l, const float* __restrict__ W2r,
    ushort_t* __restrict__ wpack, int* __restrict__ cnt)
{
    const int b = blockIdx.x;
    if (b < PACK_BLKS) {
        const int tid = b * 256 + threadIdx.x;
        if (tid < 16384)      pack_one(W1l, wpack,          IN_C,  HID_C, tid);
        else if (tid < 32768) pack_one(W1r, wpack + 16384,  IN_C,  HID_C, tid - 16384);
        else if (tid < 40960) pack_one(W2l, wpack + 32768,  HID_C, OUT_C, tid - 32768);
        else if (tid < 49152) pack_one(W2r, wpack + 40960,  HID_C, OUT_C, tid - 40960);
    } else {
        const int z = b - PACK_BLKS;
        for (int i = z * 256 + threadIdx.x; i < NPAD; i += ZERO_BLKS * 256) cnt[i] = 0;
    }
}

// ---------------------------------------------------------------------------
// mm1 body: p1f = fp8(x @ W1l), t1b = bf16(x @ W1r). Depth-2 x pipeline.
// ---------------------------------------------------------------------------
__device__ inline void mm1_body(int bid, const float* __restrict__ x,
                                const ushort_t* __restrict__ wpack,
                                uchar_t* __restrict__ p1f, ushort_t* __restrict__ t1b)
{
    const int wave = threadIdx.x >> 6;
    const int lane = threadIdx.x & 63;
    const int quad = lane >> 4;
    const int m    = lane & 15;
    const int row0 = bid * 64 + wave * 16;
    const int arow = min(row0 + m, N_NODES - 1);

    const bf16x8* Bl = (const bf16x8*)(wpack);
    const bf16x8* Br = (const bf16x8*)(wpack + 16384);

    f32x4 accl[8], accr[8];
#pragma unroll
    for (int ct = 0; ct < 8; ++ct) { accl[ct] = (f32x4)(0.0f); accr[ct] = (f32x4)(0.0f); }

    const float* xbase = x + (size_t)arow * IN_C + quad * 8;
    float4 c0 = *(const float4*)(xbase);
    float4 c1 = *(const float4*)(xbase + 4);

#pragma unroll
    for (int kt = 0; kt < 4; ++kt) {
        float4 n0 = c0, n1 = c1;
        if (kt < 3) {
            n0 = *(const float4*)(xbase + (kt + 1) * 32);
            n1 = *(const float4*)(xbase + (kt + 1) * 32 + 4);
        }
        bf16x8 af;
        af[0] = (short)f2bf(c0.x); af[1] = (short)f2bf(c0.y);
        af[2] = (short)f2bf(c0.z); af[3] = (short)f2bf(c0.w);
        af[4] = (short)f2bf(c1.x); af[5] = (short)f2bf(c1.y);
        af[6] = (short)f2bf(c1.z); af[7] = (short)f2bf(c1.w);
#pragma unroll
        for (int ct = 0; ct < 8; ++ct) {
            const bf16x8 bl = Bl[(ct * 4 + kt) * 64 + lane];
            const bf16x8 br = Br[(ct * 4 + kt) * 64 + lane];
            accl[ct] = __builtin_amdgcn_mfma_f32_16x16x32_bf16(af, bl, accl[ct], 0, 0, 0);
            accr[ct] = __builtin_amdgcn_mfma_f32_16x16x32_bf16(af, br, accr[ct], 0, 0, 0);
        }
        c0 = n0; c1 = n1;
    }

#pragma unroll
    for (int r = 0; r < 4; ++r) {
        const int orow = row0 + quad * 4 + r;
        if (orow < N_NODES) {
#pragma unroll
            for (int ct = 0; ct < 8; ++ct) {
                const int col = ct * 16 + m;
                p1f[(size_t)orow * HID_C + col] = f2fp8(accl[ct][r]);
                t1b[(size_t)orow * HID_C + col] = f2bf(accr[ct][r]);
            }
        }
    }
}

// ---------------------------------------------------------------------------
// K1: mm1 (blocks 0..781) | direct-CSR scatter (blocks 782..1172).
// Scatter: p = atomicAdd(&cnt[dst],1); csr[dst*64+p] = src. No LDS at all.
// ---------------------------------------------------------------------------
__global__ __launch_bounds__(256) void k1_kernel(
    const float* __restrict__ x, const ushort_t* __restrict__ wpack,
    uchar_t* __restrict__ p1f, ushort_t* __restrict__ t1b,
    const int* __restrict__ src, const int* __restrict__ dst,
    int* cnt, int* __restrict__ csr)
{
    const int b = blockIdx.x;
    if (b < MM1_BLKS) {
        mm1_body(b, x, wpack, p1f, t1b);
        return;
    }
    const int blk = b - MM1_BLKS;
    const int t = threadIdx.x;
    const int e0 = blk * EPB + t * 8;        // N_EDGES % 8 == 0 -> chunk all-or-nothing
    if (e0 < N_EDGES) {
        const int4 sa = *(const int4*)&src[e0];
        const int4 sb = *(const int4*)&src[e0 + 4];
        const int4 da = *(const int4*)&dst[e0];
        const int4 db = *(const int4*)&dst[e0 + 4];
        const int s8a[8] = {sa.x, sa.y, sa.z, sa.w, sb.x, sb.y, sb.z, sb.w};
        const int d8a[8] = {da.x, da.y, da.z, da.w, db.x, db.y, db.z, db.w};
#pragma unroll
        for (int j = 0; j < 8; ++j) {
            const int d = d8a[j];
            const int p = atomicAdd(&cnt[d], 1);
            if (p < DCAP) csr[d * DCAP + p] = s8a[j];
        }
    }
}

// ---------------------------------------------------------------------------
// l2f: fused agg1 + mm2. One block per 32-node bin (1564 blocks).
// Phase 0: stage this bin's csr region (8KB, coalesced) + cnt into LDS.
// Phase A: gather-mean + h into LDS (8 lanes/node, unroll-4).
// Phase B: MFMA per wave half-rows.
// ---------------------------------------------------------------------------
__global__ __launch_bounds__(256, 4) void l2f_kernel(
    const int* __restrict__ cnt, const int* __restrict__ csr,
    const uchar_t* __restrict__ p1f, const ushort_t* __restrict__ t1b,
    const float* __restrict__ b1, const ushort_t* __restrict__ wpack,
    uchar_t* __restrict__ p2f, ushort_t* __restrict__ t2b)
{
    __shared__ ushort_t hs[32 * HS_STRIDE];
    __shared__ __align__(16) int csr_lds[32 * DCAP];
    __shared__ int lh[32];
    __shared__ int pool;

    const int blk = blockIdx.x;              // bin index = node >> 5
    const int tid = threadIdx.x;

    if (tid == 0) pool = 0;
    if (tid < 32) {
        const int node = blk * 32 + tid;
        lh[tid] = (node < N_NODES) ? min(cnt[node], DCAP) : 0;
    }
    // stage this bin's csr region: 2048 ints = 8KB, fully coalesced int4
    {
        const int4* s4 = (const int4*)(csr + blk * 32 * DCAP);
        int4* d4 = (int4*)csr_lds;
        for (int i = tid; i < (32 * DCAP) / 4; i += 256) d4[i] = s4[i];
    }
    __syncthreads();

    // ---- Phase A: gather-mean + h into LDS (8 lanes/node, unroll-4) ----
    const int c16 = tid & 7;                     // channels 16*c16 .. 16*c16+15
    const int gb  = (tid & 63) & 56;             // 8-lane group leader in wave
    const uint4* p1v = (const uint4*)p1f;        // row stride 8 uint4

    while (true) {
        int nl = 0;
        if (c16 == 0) nl = atomicAdd(&pool, 1);
        nl = __shfl(nl, gb, 64);
        if (nl >= 32) break;
        const int node = blk * 32 + nl;
        uint4 oL = make_uint4(0u, 0u, 0u, 0u);
        uint4 oH = make_uint4(0u, 0u, 0u, 0u);
        if (node < N_NODES) {
            const int start = nl * DCAP;
            const int degi  = lh[nl];
            // hoist independent self-path loads so they fly during the gather
            const size_t ib = (size_t)node * HID_C + c16 * 16;
            const uint4 tvL = *(const uint4*)(t1b + ib);
            const uint4 tvH = *(const uint4*)(t1b + ib + 8);
            float a[16];
#pragma unroll
            for (int z = 0; z < 16; ++z) a[z] = 0.0f;
            int e = 0;
            for (; e + 3 < degi; e += 4) {
                const int s0 = csr_lds[start + e + 0];
                const int s1 = csr_lds[start + e + 1];
                const int s2 = csr_lds[start + e + 2];
                const int s3 = csr_lds[start + e + 3];
                const uint4 w0 = p1v[(size_t)s0 * 8 + c16];
                const uint4 w1 = p1v[(size_t)s1 * 8 + c16];
                const uint4 w2 = p1v[(size_t)s2 * 8 + c16];
                const uint4 w3 = p1v[(size_t)s3 * 8 + c16];
                acc_uint4(a, w0); acc_uint4(a, w1); acc_uint4(a, w2); acc_uint4(a, w3);
            }
            for (; e < degi; ++e) {
                const uint4 v = p1v[(size_t)csr_lds[start + e] * 8 + c16];
                acc_uint4(a, v);
            }
            const float inv = 1.0f / fmaxf((float)degi, 1.0f);
            float r[16];
#pragma unroll
            for (int z = 0; z < 4; ++z) {
                const float4 bv = *(const float4*)(b1 + c16 * 16 + z * 4);
                r[z*4+0] = bv.x; r[z*4+1] = bv.y; r[z*4+2] = bv.z; r[z*4+3] = bv.w;
            }
            const uint_t tw[8] = {tvL.x, tvL.y, tvL.z, tvL.w, tvH.x, tvH.y, tvH.z, tvH.w};
#pragma unroll
            for (int z = 0; z < 8; ++z) {
                r[z*2+0] = fmaxf(fmaf(a[z*2+0], inv, r[z*2+0] + bflo(tw[z])), 0.0f);
                r[z*2+1] = fmaxf(fmaf(a[z*2+1], inv, r[z*2+1] + bfhi(tw[z])), 0.0f);
            }
            oL.x = (uint_t)f2bf(r[0])  | ((uint_t)f2bf(r[1])  << 16);
            oL.y = (uint_t)f2bf(r[2])  | ((uint_t)f2bf(r[3])  << 16);
            oL.z = (uint_t)f2bf(r[4])  | ((uint_t)f2bf(r[5])  << 16);
            oL.w = (uint_t)f2bf(r[6])  | ((uint_t)f2bf(r[7])  << 16);
            oH.x = (uint_t)f2bf(r[8])  | ((uint_t)f2bf(r[9])  << 16);
            oH.y = (uint_t)f2bf(r[10]) | ((uint_t)f2bf(r[11]) << 16);
            oH.z = (uint_t)f2bf(r[12]) | ((uint_t)f2bf(r[13]) << 16);
            oH.w = (uint_t)f2bf(r[14]) | ((uint_t)f2bf(r[15]) << 16);
        }
        *(uint4*)&hs[nl * HS_STRIDE + c16 * 16] = oL;
        *(uint4*)&hs[nl * HS_STRIDE + c16 * 16 + 8] = oH;
    }
    __syncthreads();

    // ---- Phase B: MFMA. Wave wv -> rows (wv&1)*16..+15, ct (wv>>1)*2..+1. ----
    const int wv    = tid >> 6;
    const int lane  = tid & 63;
    const int quad  = lane >> 4;
    const int m     = lane & 15;
    const int rhalf = wv & 1;
    const int chalf = (wv >> 1) * 2;
    const int row0  = blk * 32 + rhalf * 16;

    const bf16x8* Bl = (const bf16x8*)(wpack + 32768);
    const bf16x8* Br = (const bf16x8*)(wpack + 40960);

    f32x4 accl[2], accr[2];
#pragma unroll
    for (int c2 = 0; c2 < 2; ++c2) { accl[c2] = (f32x4)(0.0f); accr[c2] = (f32x4)(0.0f); }

#pragma unroll
    for (int kt = 0; kt < 4; ++kt) {
        const bf16x8 af = *(const bf16x8*)&hs[(rhalf * 16 + m) * HS_STRIDE + kt * 32 + quad * 8];
#pragma unroll
        for (int c2 = 0; c2 < 2; ++c2) {
            const int ct = chalf + c2;
            const bf16x8 bl = Bl[(ct * 4 + kt) * 64 + lane];
            const bf16x8 br = Br[(ct * 4 + kt) * 64 + lane];
            accl[c2] = __builtin_amdgcn_mfma_f32_16x16x32_bf16(af, bl, accl[c2], 0, 0, 0);
            accr[c2] = __builtin_amdgcn_mfma_f32_16x16x32_bf16(af, br, accr[c2], 0, 0, 0);
        }
    }

#pragma unroll
    for (int r = 0; r < 4; ++r) {
        const int orow = row0 + quad * 4 + r;
        if (orow < N_NODES) {
#pragma unroll
            for (int c2 = 0; c2 < 2; ++c2) {
                const int col = (chalf + c2) * 16 + m;
                p2f[(size_t)orow * OUT_C + col] = f2fp8(accl[c2][r]);
                t2b[(size_t)orow * OUT_C + col] = f2bf(accr[c2][r]);
            }
        }
    }
}

// ---------------------------------------------------------------------------
// agg2: 64 nodes/block, 4 lanes/node, unroll-4, csr read direct (fixed rows).
// out = mean(p2[src]) + b2 + t2.
// ---------------------------------------------------------------------------
__global__ __launch_bounds__(256) void agg2_kernel(
    const uchar_t* __restrict__ p2f, const ushort_t* __restrict__ t2b,
    const float* __restrict__ b2, const int* __restrict__ cnt,
    const int* __restrict__ csr, float* __restrict__ out)
{
    const int c16 = threadIdx.x & 3;           // channels 16*c16 .. 16*c16+15
    const int grp = threadIdx.x >> 2;          // 0..63
    const uint4* p2v = (const uint4*)p2f;      // row stride 4 uint4

    const int node = blockIdx.x * 64 + grp;
    if (node >= N_NODES) return;
    const int start = node * DCAP;
    const int degi  = min(cnt[node], DCAP);
    // hoist independent self-path loads
    const size_t i = (size_t)node * OUT_C + c16 * 16;
    const uint4 tvL = *(const uint4*)(t2b + i);
    const uint4 tvH = *(const uint4*)(t2b + i + 8);
    float a[16];
#pragma unroll
    for (int z = 0; z < 16; ++z) a[z] = 0.0f;
    int e = 0;
    for (; e + 3 < degi; e += 4) {
        const int s0 = csr[start + e + 0];
        const int s1 = csr[start + e + 1];
        const int s2 = csr[start + e + 2];
        const int s3 = csr[start + e + 3];
        const uint4 w0 = p2v[(size_t)s0 * 4 + c16];
        const uint4 w1 = p2v[(size_t)s1 * 4 + c16];
        const uint4 w2 = p2v[(size_t)s2 * 4 + c16];
        const uint4 w3 = p2v[(size_t)s3 * 4 + c16];
        acc_uint4(a, w0); acc_uint4(a, w1); acc_uint4(a, w2); acc_uint4(a, w3);
    }
    for (; e < degi; ++e) {
        const uint4 v = p2v[(size_t)csr[start + e] * 4 + c16];
        acc_uint4(a, v);
    }

    const float inv = 1.0f / fmaxf((float)degi, 1.0f);
    const uint_t tw[8] = {tvL.x, tvL.y, tvL.z, tvL.w, tvH.x, tvH.y, tvH.z, tvH.w};
#pragma unroll
    for (int z = 0; z < 4; ++z) {
        const float4 bv = *(const float4*)(b2 + c16 * 16 + z * 4);
        float4 o;
        o.x = fmaf(a[z*4+0], inv, bv.x + bflo(tw[z*2+0]));
        o.y = fmaf(a[z*4+1], inv, bv.y + bfhi(tw[z*2+0]));
        o.z = fmaf(a[z*4+2], inv, bv.z + bflo(tw[z*2+1]));
        o.w = fmaf(a[z*4+3], inv, bv.w + bfhi(tw[z*2+1]));
        *(float4*)(out + i + z * 4) = o;
    }
}

extern "C" void kernel_launch(void* const* d_in, const int* in_sizes, int n_in,
                              void* d_out, int out_size, void* d_ws, size_t ws_size,
                              hipStream_t stream)
{
    const float* x   = (const float*)d_in[0];
    const int*   ei  = (const int*)d_in[1];
    const float* W1l = (const float*)d_in[2];
    const float* b1  = (const float*)d_in[3];
    const float* W1r = (const float*)d_in[4];
    const float* W2l = (const float*)d_in[5];
    const float* b2  = (const float*)d_in[6];
    const float* W2r = (const float*)d_in[7];
    float* out = (float*)d_out;

    const int* src = ei;
    const int* dst = ei + N_EDGES;

    const size_t NH = (size_t)N_NODES * HID_C;   // 6.4M
    const size_t NO = (size_t)N_NODES * OUT_C;   // 3.2M
    const size_t CS = (size_t)NPAD * DCAP;       // 3.2M csr slots (12.8MB)

    // Workspace layout (all offsets stay 16B-aligned; sizes are x16 multiples).
    char* ws = (char*)d_ws;
    ushort_t* t1b   = (ushort_t*)ws;                   ws += NH * sizeof(ushort_t);
    ushort_t* t2b   = (ushort_t*)ws;                   ws += NO * sizeof(ushort_t);
    ushort_t* wpack = (ushort_t*)ws;                   ws += 49152 * sizeof(ushort_t);
    int* csr     = (int*)ws;                           ws += CS * sizeof(int);
    int* cnt     = (int*)ws;                           ws += NPAD * sizeof(int);
    uchar_t* p1f = (uchar_t*)ws;                       ws += NH * sizeof(uchar_t);
    uchar_t* p2f = (uchar_t*)ws;                       ws += NO * sizeof(uchar_t);

    const size_t need = (size_t)(ws - (char*)d_ws);
    if (ws_size < need) return;

    // K0: pack weights | zero cnt                  (input-only)
    k0_kernel<<<PACK_BLKS + ZERO_BLKS, 256, 0, stream>>>(W1l, W1r, W2l, W2r, wpack, cnt);
    // K1: mm1 | direct-CSR scatter                 (reads K0 outputs/inputs)
    k1_kernel<<<MM1_BLKS + EBLKS, 256, 0, stream>>>(
        x, wpack, p1f, t1b, src, dst, cnt, csr);
    // Fused agg1 + mm2 (one block per 32-node bin; csr staged from fixed rows)
    l2f_kernel<<<NBIN, 256, 0, stream>>>(
        cnt, csr, p1f, t1b, b1, wpack, p2f, t2b);
    // Final aggregation (csr direct)
    agg2_kernel<<<MM1_BLKS, 256, 0, stream>>>(
        p2f, t2b, b2, cnt, csr, out);
}

// Round 9
// 152.132 us; speedup vs baseline: 1.2540x; 1.2540x over previous
//
#include <hip/hip_runtime.h>

#define N_NODES 50000
#define N_EDGES 800000
#define IN_C    128
#define HID_C   128
#define OUT_C   64
#define NQ      784                         // quarter-buckets (node>>6): 782 used + 2 empty pad
#define QBCAP   1536                        // slots per quarter bucket (mean 1020 -> ~16 sigma)
#define QCAP    1536                        // csr slots per quarter
#define EPB     4096                        // edges per scatter block (16/thread, staged)
#define EBLKS   ((N_EDGES + EPB - 1) / EPB) // 196
#define PACK_BLKS 192
#define MM1_BLKS  ((N_NODES + 63) / 64)     // 782
#define L2F_BLKS  NQ                        // one block per quarter bucket
#define HS_STRIDE 136                       // 128 ushorts + 8 pad -> 272B rows

typedef unsigned short ushort_t;
typedef unsigned int   uint_t;
typedef unsigned char  uchar_t;
typedef __attribute__((ext_vector_type(8))) short bf16x8;
typedef __attribute__((ext_vector_type(4))) float f32x4;
typedef __attribute__((ext_vector_type(2))) float f32x2;

__device__ inline ushort_t f2bf(float f) {
    uint_t u = __float_as_uint(f);
    uint_t r = (u + 0x7fffu + ((u >> 16) & 1u)) >> 16;
    return (ushort_t)r;
}
__device__ inline float bflo(uint_t v) { return __uint_as_float(v << 16); }
__device__ inline float bfhi(uint_t v) { return __uint_as_float(v & 0xffff0000u); }
__device__ inline uchar_t f2fp8(float v) {
    return (uchar_t)(__builtin_amdgcn_cvt_pk_fp8_f32(v, v, 0, false) & 0xff);
}
// decode one dword = 4 fp8 -> acc[0..3]
__device__ inline void acc_fp8x4(float* a, uint_t d) {
    const f32x2 lo = __builtin_amdgcn_cvt_pk_f32_fp8((int)d, false);
    const f32x2 hi = __builtin_amdgcn_cvt_pk_f32_fp8((int)d, true);
    a[0] += lo.x; a[1] += lo.y; a[2] += hi.x; a[3] += hi.y;
}
__device__ inline void acc_uint4(float* a, const uint4 v) {
    acc_fp8x4(a + 0,  v.x);
    acc_fp8x4(a + 4,  v.y);
    acc_fp8x4(a + 8,  v.z);
    acc_fp8x4(a + 12, v.w);
}

// ---------------------------------------------------------------------------
// Weight pre-pack into B-fragment order for mfma_f32_16x16x32_bf16.
// ---------------------------------------------------------------------------
__device__ inline void pack_one(const float* W, ushort_t* Wp, int K, int N, int idx) {
    const int j  = idx & 7;
    const int L  = (idx >> 3) & 63;
    const int t  = idx >> 9;
    const int KT = K / 32;
    const int kt = t % KT;
    const int ct = t / KT;
    const int k  = kt * 32 + (L >> 4) * 8 + j;
    const int n  = ct * 16 + (L & 15);
    Wp[idx] = f2bf(W[k * N + n]);
}

// ---------------------------------------------------------------------------
// K0: pack weights (blocks 0..191) | zero quarter-bucket cursors (block 192).
// ---------------------------------------------------------------------------
__global__ __launch_bounds__(256) void k0_kernel(
    const float* __restrict__ W1l, const float* __restrict__ W1r,
    const float* __restrict__ W2l, const float* __restrict__ W2r,
    ushort_t* __restrict__ wpack, int* __restrict__ gcur)
{
    const int b = blockIdx.x;
    if (b < PACK_BLKS) {
        const int tid = b * 256 + threadIdx.x;
        if (tid < 16384)      pack_one(W1l, wpack,          IN_C,  HID_C, tid);
        else if (tid < 32768) pack_one(W1r, wpack + 16384,  IN_C,  HID_C, tid - 16384);
        else if (tid < 40960) pack_one(W2l, wpack + 32768,  HID_C, OUT_C, tid - 32768);
        else if (tid < 49152) pack_one(W2r, wpack + 40960,  HID_C, OUT_C, tid - 40960);
    } else {
        for (int i = threadIdx.x; i < NQ; i += 256) gcur[i] = 0;
    }
}

// ---------------------------------------------------------------------------
// mm1 body: p1f = fp8(x @ W1l), t1b = bf16(x @ W1r). wpack from K0.
// ---------------------------------------------------------------------------
__device__ inline void mm1_body(int bid, const float* __restrict__ x,
                                const ushort_t* __restrict__ wpack,
                                uchar_t* __restrict__ p1f, ushort_t* __restrict__ t1b)
{
    const int wave = threadIdx.x >> 6;
    const int lane = threadIdx.x & 63;
    const int quad = lane >> 4;
    const int m    = lane & 15;
    const int row0 = bid * 64 + wave * 16;
    const int arow = min(row0 + m, N_NODES - 1);

    const bf16x8* Bl = (const bf16x8*)(wpack);
    const bf16x8* Br = (const bf16x8*)(wpack + 16384);

    f32x4 accl[8], accr[8];
#pragma unroll
    for (int ct = 0; ct < 8; ++ct) { accl[ct] = (f32x4)(0.0f); accr[ct] = (f32x4)(0.0f); }

#pragma unroll
    for (int kt = 0; kt < 4; ++kt) {
        const float* xp = x + (size_t)arow * IN_C + kt * 32 + quad * 8;
        const float4 a0 = *(const float4*)(xp);
        const float4 a1 = *(const float4*)(xp + 4);
        bf16x8 af;
        af[0] = (short)f2bf(a0.x); af[1] = (short)f2bf(a0.y);
        af[2] = (short)f2bf(a0.z); af[3] = (short)f2bf(a0.w);
        af[4] = (short)f2bf(a1.x); af[5] = (short)f2bf(a1.y);
        af[6] = (short)f2bf(a1.z); af[7] = (short)f2bf(a1.w);
#pragma unroll
        for (int ct = 0; ct < 8; ++ct) {
            const bf16x8 bl = Bl[(ct * 4 + kt) * 64 + lane];
            const bf16x8 br = Br[(ct * 4 + kt) * 64 + lane];
            accl[ct] = __builtin_amdgcn_mfma_f32_16x16x32_bf16(af, bl, accl[ct], 0, 0, 0);
            accr[ct] = __builtin_amdgcn_mfma_f32_16x16x32_bf16(af, br, accr[ct], 0, 0, 0);
        }
    }

#pragma unroll
    for (int r = 0; r < 4; ++r) {
        const int orow = row0 + quad * 4 + r;
        if (orow < N_NODES) {
#pragma unroll
            for (int ct = 0; ct < 8; ++ct) {
                const int col = ct * 16 + m;
                p1f[(size_t)orow * HID_C + col] = f2fp8(accl[ct][r]);
                t1b[(size_t)orow * HID_C + col] = f2bf(accr[ct][r]);
            }
        }
    }
}

// ---------------------------------------------------------------------------
// K1: quarter-bucket scatter FIRST (blocks 0..195) | mm1 (blocks 196..977).
// Scatter blocks start earliest -> their atomic latency overlaps mm1 fully.
// 16 edges/thread staged in registers; N_EDGES % 16 == 0 -> all-or-nothing.
// ---------------------------------------------------------------------------
__global__ __launch_bounds__(256) void k1_kernel(
    const float* __restrict__ x, const ushort_t* __restrict__ wpack,
    uchar_t* __restrict__ p1f, ushort_t* __restrict__ t1b,
    const int* __restrict__ src, const int* __restrict__ dst,
    int* gcur, int* __restrict__ ebuf)
{
    __shared__ int lh[NQ], gb2[NQ], lc[NQ];
    const int b = blockIdx.x;
    if (b >= EBLKS) {
        mm1_body(b - EBLKS, x, wpack, p1f, t1b);
        return;
    }
    const int blk = b;
    const int t = threadIdx.x;
    for (int i = t; i < NQ; i += 256) lh[i] = 0;
    __syncthreads();
    const int e0 = blk * EPB + t * 16;
    int v16[16], b16[16];
    if (e0 < N_EDGES) {
        const int4 sa0 = *(const int4*)&src[e0];
        const int4 sa1 = *(const int4*)&src[e0 + 4];
        const int4 sa2 = *(const int4*)&src[e0 + 8];
        const int4 sa3 = *(const int4*)&src[e0 + 12];
        const int4 da0 = *(const int4*)&dst[e0];
        const int4 da1 = *(const int4*)&dst[e0 + 4];
        const int4 da2 = *(const int4*)&dst[e0 + 8];
        const int4 da3 = *(const int4*)&dst[e0 + 12];
        const int s16[16] = {sa0.x, sa0.y, sa0.z, sa0.w, sa1.x, sa1.y, sa1.z, sa1.w,
                             sa2.x, sa2.y, sa2.z, sa2.w, sa3.x, sa3.y, sa3.z, sa3.w};
        const int d16[16] = {da0.x, da0.y, da0.z, da0.w, da1.x, da1.y, da1.z, da1.w,
                             da2.x, da2.y, da2.z, da2.w, da3.x, da3.y, da3.z, da3.w};
#pragma unroll
        for (int j = 0; j < 16; ++j) {
            b16[j] = d16[j] >> 6;                      // quarter bucket
            v16[j] = (s16[j] << 6) | (d16[j] & 63);    // src | node-in-quarter
            atomicAdd(&lh[b16[j]], 1);
        }
    } else {
#pragma unroll
        for (int j = 0; j < 16; ++j) b16[j] = -1;
    }
    __syncthreads();
    for (int i = t; i < NQ; i += 256) {
        const int run = lh[i];
        gb2[i] = (run > 0) ? atomicAdd(&gcur[i], run) : 0;
        lc[i] = 0;
    }
    __syncthreads();
#pragma unroll
    for (int j = 0; j < 16; ++j) {
        const int bk = b16[j];
        if (bk >= 0) {
            const int p   = atomicAdd(&lc[bk], 1);
            const int pos = gb2[bk] + p;
            if (pos < QBCAP) ebuf[bk * QBCAP + pos] = v16[j];
        }
    }
}

// ---------------------------------------------------------------------------
// l2f: fused fill + agg1 + mm2. One block per QUARTER-bucket (64 nodes).
// Phase 0: single global pass, reg-staged (<=6 ints/thread, static indexing).
// Phase A: 8 lanes/node, uint4 (16 fp8 ch) loads, self-path loads hoisted.
// ---------------------------------------------------------------------------
__global__ __launch_bounds__(256, 4) void l2f_kernel(
    const int* __restrict__ ebuf, const int* __restrict__ gcur,
    int* __restrict__ cnt, int* __restrict__ row_ptr, int* __restrict__ csr_g,
    const uchar_t* __restrict__ p1f, const ushort_t* __restrict__ t1b,
    const float* __restrict__ b1,
    const ushort_t* __restrict__ wpack,
    uchar_t* __restrict__ p2f, ushort_t* __restrict__ t2b)
{
    __shared__ ushort_t hs[64 * HS_STRIDE];
    __shared__ int csr_lds[QCAP];
    __shared__ int lh[64], lstart[64], lcur2[64];
    __shared__ int pool;

    const int blk = blockIdx.x;              // quarter index = node >> 6
    const int tid = threadIdx.x;

    if (tid == 0) pool = 0;
    if (tid < 64) lh[tid] = 0;
    __syncthreads();

    // ---- Phase 0: single pass over OWN quarter's run, staged in registers ----
    const int nb   = min(gcur[blk], QBCAP);
    const int base = blk * QBCAP;
    int v0 = -1, v1 = -1, v2 = -1, v3 = -1, v4 = -1, v5 = -1;
    if (tid        < nb) v0 = ebuf[base + tid];
    if (tid + 256  < nb) v1 = ebuf[base + tid + 256];
    if (tid + 512  < nb) v2 = ebuf[base + tid + 512];
    if (tid + 768  < nb) v3 = ebuf[base + tid + 768];
    if (tid + 1024 < nb) v4 = ebuf[base + tid + 1024];
    if (tid + 1280 < nb) v5 = ebuf[base + tid + 1280];
    if (v0 >= 0) atomicAdd(&lh[v0 & 63], 1);
    if (v1 >= 0) atomicAdd(&lh[v1 & 63], 1);
    if (v2 >= 0) atomicAdd(&lh[v2 & 63], 1);
    if (v3 >= 0) atomicAdd(&lh[v3 & 63], 1);
    if (v4 >= 0) atomicAdd(&lh[v4 & 63], 1);
    if (v5 >= 0) atomicAdd(&lh[v5 & 63], 1);
    __syncthreads();
    int scanv = 0;
    if (tid < 64) scanv = lh[tid];
    if (tid < 64) lcur2[tid] = scanv;
    __syncthreads();
#pragma unroll
    for (int off = 1; off < 64; off <<= 1) {
        int add = 0;
        if (tid < 64 && tid >= off) add = lcur2[tid - off];
        __syncthreads();
        if (tid < 64) lcur2[tid] += add;
        __syncthreads();
    }
    if (tid < 64) {
        const int ex = lcur2[tid] - scanv;       // exclusive offset
        lstart[tid] = ex;
        const int node = blk * 64 + tid;
        if (node < N_NODES) { cnt[node] = scanv; row_ptr[node] = blk * QCAP + ex; }
    }
    __syncthreads();
    if (tid < 64) lcur2[tid] = lstart[tid];      // running cursors
    __syncthreads();
    if (v0 >= 0) { const int p = atomicAdd(&lcur2[v0 & 63], 1); if (p < QCAP) csr_lds[p] = v0 >> 6; }
    if (v1 >= 0) { const int p = atomicAdd(&lcur2[v1 & 63], 1); if (p < QCAP) csr_lds[p] = v1 >> 6; }
    if (v2 >= 0) { const int p = atomicAdd(&lcur2[v2 & 63], 1); if (p < QCAP) csr_lds[p] = v2 >> 6; }
    if (v3 >= 0) { const int p = atomicAdd(&lcur2[v3 & 63], 1); if (p < QCAP) csr_lds[p] = v3 >> 6; }
    if (v4 >= 0) { const int p = atomicAdd(&lcur2[v4 & 63], 1); if (p < QCAP) csr_lds[p] = v4 >> 6; }
    if (v5 >= 0) { const int p = atomicAdd(&lcur2[v5 & 63], 1); if (p < QCAP) csr_lds[p] = v5 >> 6; }
    __syncthreads();
    // stream csr to global (coalesced) for agg2
    {
        const int total = lcur2[63] > QCAP ? QCAP : lcur2[63];
        for (int i = tid; i < total; i += 256) csr_g[blk * QCAP + i] = csr_lds[i];
    }
    __syncthreads();

    // ---- Phase A: gather-mean + h into LDS (8 lanes/node, uint4 loads) ----
    const int c16 = tid & 7;                     // channels 16*c16 .. 16*c16+15
    const int gb  = (tid & 63) & 56;             // 8-lane group leader in wave
    const uint4* p1v = (const uint4*)p1f;        // row stride 8 uint4

    while (true) {
        int nl = 0;
        if (c16 == 0) nl = atomicAdd(&pool, 1);
        nl = __shfl(nl, gb, 64);
        if (nl >= 64) break;
        const int node = blk * 64 + nl;
        uint4 oL = make_uint4(0u, 0u, 0u, 0u);
        uint4 oH = make_uint4(0u, 0u, 0u, 0u);
        if (node < N_NODES) {
            const int start = lstart[nl];
            const int degi  = lh[nl];
            // hoist independent self-path loads so they fly during the gather
            const size_t ib = (size_t)node * HID_C + c16 * 16;
            const uint4 tvL = *(const uint4*)(t1b + ib);
            const uint4 tvH = *(const uint4*)(t1b + ib + 8);
            float a[16];
#pragma unroll
            for (int z = 0; z < 16; ++z) a[z] = 0.0f;
            int e = 0;
            for (; e + 3 < degi; e += 4) {
                const int s0 = csr_lds[start + e];
                const int s1 = csr_lds[start + e + 1];
                const int s2 = csr_lds[start + e + 2];
                const int s3 = csr_lds[start + e + 3];
                const uint4 w0 = p1v[(size_t)s0 * 8 + c16];
                const uint4 w1 = p1v[(size_t)s1 * 8 + c16];
                const uint4 w2 = p1v[(size_t)s2 * 8 + c16];
                const uint4 w3 = p1v[(size_t)s3 * 8 + c16];
                acc_uint4(a, w0); acc_uint4(a, w1); acc_uint4(a, w2); acc_uint4(a, w3);
            }
            for (; e < degi; ++e) {
                const uint4 v = p1v[(size_t)csr_lds[start + e] * 8 + c16];
                acc_uint4(a, v);
            }
            const float inv = 1.0f / fmaxf((float)degi, 1.0f);
            float r[16];
#pragma unroll
            for (int z = 0; z < 4; ++z) {
                const float4 bv = *(const float4*)(b1 + c16 * 16 + z * 4);
                r[z*4+0] = bv.x; r[z*4+1] = bv.y; r[z*4+2] = bv.z; r[z*4+3] = bv.w;
            }
            const uint_t tw[8] = {tvL.x, tvL.y, tvL.z, tvL.w, tvH.x, tvH.y, tvH.z, tvH.w};
#pragma unroll
            for (int z = 0; z < 8; ++z) {
                r[z*2+0] = fmaxf(fmaf(a[z*2+0], inv, r[z*2+0] + bflo(tw[z])), 0.0f);
                r[z*2+1] = fmaxf(fmaf(a[z*2+1], inv, r[z*2+1] + bfhi(tw[z])), 0.0f);
            }
            oL.x = (uint_t)f2bf(r[0])  | ((uint_t)f2bf(r[1])  << 16);
            oL.y = (uint_t)f2bf(r[2])  | ((uint_t)f2bf(r[3])  << 16);
            oL.z = (uint_t)f2bf(r[4])  | ((uint_t)f2bf(r[5])  << 16);
            oL.w = (uint_t)f2bf(r[6])  | ((uint_t)f2bf(r[7])  << 16);
            oH.x = (uint_t)f2bf(r[8])  | ((uint_t)f2bf(r[9])  << 16);
            oH.y = (uint_t)f2bf(r[10]) | ((uint_t)f2bf(r[11]) << 16);
            oH.z = (uint_t)f2bf(r[12]) | ((uint_t)f2bf(r[13]) << 16);
            oH.w = (uint_t)f2bf(r[14]) | ((uint_t)f2bf(r[15]) << 16);
        }
        *(uint4*)&hs[nl * HS_STRIDE + c16 * 16] = oL;
        *(uint4*)&hs[nl * HS_STRIDE + c16 * 16 + 8] = oH;
    }
    __syncthreads();

    // ---- Phase B: MFMA. Wave wv owns rows wv*16..wv*16+15. ----
    const int wv   = tid >> 6;
    const int lane = tid & 63;
    const int quad = lane >> 4;
    const int m    = lane & 15;
    const int row0 = blk * 64 + wv * 16;

    const bf16x8* Bl = (const bf16x8*)(wpack + 32768);
    const bf16x8* Br = (const bf16x8*)(wpack + 40960);

    f32x4 accl[4], accr[4];
#pragma unroll
    for (int ct = 0; ct < 4; ++ct) { accl[ct] = (f32x4)(0.0f); accr[ct] = (f32x4)(0.0f); }

#pragma unroll
    for (int kt = 0; kt < 4; ++kt) {
        const bf16x8 af = *(const bf16x8*)&hs[(wv * 16 + m) * HS_STRIDE + kt * 32 + quad * 8];
#pragma unroll
        for (int ct = 0; ct < 4; ++ct) {
            const bf16x8 bl = Bl[(ct * 4 + kt) * 64 + lane];
            const bf16x8 br = Br[(ct * 4 + kt) * 64 + lane];
            accl[ct] = __builtin_amdgcn_mfma_f32_16x16x32_bf16(af, bl, accl[ct], 0, 0, 0);
            accr[ct] = __builtin_amdgcn_mfma_f32_16x16x32_bf16(af, br, accr[ct], 0, 0, 0);
        }
    }

#pragma unroll
    for (int r = 0; r < 4; ++r) {
        const int orow = row0 + quad * 4 + r;
        if (orow < N_NODES) {
#pragma unroll
            for (int ct = 0; ct < 4; ++ct) {
                const int col = ct * 16 + m;
                p2f[(size_t)orow * OUT_C + col] = f2fp8(accl[ct][r]);
                t2b[(size_t)orow * OUT_C + col] = f2bf(accr[ct][r]);
            }
        }
    }
}

// ---------------------------------------------------------------------------
// agg2: 64 nodes/block, 4 lanes/node, uint4 loads (16 fp8 ch/lane).
// out = mean(p2[src]) + b2 + t2.
// ---------------------------------------------------------------------------
__global__ __launch_bounds__(256) void agg2_kernel(
    const uchar_t* __restrict__ p2f, const ushort_t* __restrict__ t2b,
    const float* __restrict__ b2, const int* __restrict__ row_ptr,
    const int* __restrict__ cnt, const int* __restrict__ csr,
    float* __restrict__ out)
{
    const int c16 = threadIdx.x & 3;           // channels 16*c16 .. 16*c16+15
    const int grp = threadIdx.x >> 2;          // 0..63
    const uint4* p2v = (const uint4*)p2f;      // row stride 4 uint4

    const int node = blockIdx.x * 64 + grp;
    if (node >= N_NODES) return;
    const int start = row_ptr[node];
    const int degi  = cnt[node];
    // hoist independent self-path loads
    const size_t i = (size_t)node * OUT_C + c16 * 16;
    const uint4 tvL = *(const uint4*)(t2b + i);
    const uint4 tvH = *(const uint4*)(t2b + i + 8);
    float a[16];
#pragma unroll
    for (int z = 0; z < 16; ++z) a[z] = 0.0f;
    int e = 0;
    for (; e + 3 < degi; e += 4) {
        const int s0 = csr[start + e];
        const int s1 = csr[start + e + 1];
        const int s2 = csr[start + e + 2];
        const int s3 = csr[start + e + 3];
        const uint4 w0 = p2v[(size_t)s0 * 4 + c16];
        const uint4 w1 = p2v[(size_t)s1 * 4 + c16];
        const uint4 w2 = p2v[(size_t)s2 * 4 + c16];
        const uint4 w3 = p2v[(size_t)s3 * 4 + c16];
        acc_uint4(a, w0); acc_uint4(a, w1); acc_uint4(a, w2); acc_uint4(a, w3);
    }
    for (; e < degi; ++e) {
        const uint4 v = p2v[(size_t)csr[start + e] * 4 + c16];
        acc_uint4(a, v);
    }

    const float inv = 1.0f / fmaxf((float)degi, 1.0f);
    const uint_t tw[8] = {tvL.x, tvL.y, tvL.z, tvL.w, tvH.x, tvH.y, tvH.z, tvH.w};
#pragma unroll
    for (int z = 0; z < 4; ++z) {
        const float4 bv = *(const float4*)(b2 + c16 * 16 + z * 4);
        float4 o;
        o.x = fmaf(a[z*4+0], inv, bv.x + bflo(tw[z*2+0]));
        o.y = fmaf(a[z*4+1], inv, bv.y + bfhi(tw[z*2+0]));
        o.z = fmaf(a[z*4+2], inv, bv.z + bflo(tw[z*2+1]));
        o.w = fmaf(a[z*4+3], inv, bv.w + bfhi(tw[z*2+1]));
        *(float4*)(out + i + z * 4) = o;
    }
}

extern "C" void kernel_launch(void* const* d_in, const int* in_sizes, int n_in,
                              void* d_out, int out_size, void* d_ws, size_t ws_size,
                              hipStream_t stream)
{
    const float* x   = (const float*)d_in[0];
    const int*   ei  = (const int*)d_in[1];
    const float* W1l = (const float*)d_in[2];
    const float* b1  = (const float*)d_in[3];
    const float* W1r = (const float*)d_in[4];
    const float* W2l = (const float*)d_in[5];
    const float* b2  = (const float*)d_in[6];
    const float* W2r = (const float*)d_in[7];
    float* out = (float*)d_out;

    const int* src = ei;
    const int* dst = ei + N_EDGES;

    const size_t NH = (size_t)N_NODES * HID_C;   // 6.4M
    const size_t NO = (size_t)N_NODES * OUT_C;   // 3.2M
    const size_t EB = (size_t)NQ * QBCAP;        // 1.204M slots
    const size_t CB = (size_t)NQ * QCAP;         // 1.204M csr slots

    // Workspace layout (8B-aligned first, bytes last). p1f/p2f 16B-aligned
    // (offsets are multiples of 16 from the 256B-aligned base).
    char* ws = (char*)d_ws;
    ushort_t* t1b   = (ushort_t*)ws;                   ws += NH * sizeof(ushort_t);
    ushort_t* t2b   = (ushort_t*)ws;                   ws += NO * sizeof(ushort_t);
    ushort_t* wpack = (ushort_t*)ws;                   ws += 49152 * sizeof(ushort_t);
    int* ebuf    = (int*)ws;                           ws += EB * sizeof(int);
    int* csr     = (int*)ws;                           ws += CB * sizeof(int);
    int* cnt     = (int*)ws;                           ws += N_NODES * sizeof(int);
    int* row_ptr = (int*)ws;                           ws += N_NODES * sizeof(int);
    int* gcur    = (int*)ws;                           ws += NQ * sizeof(int);
    ws += (16 - ((size_t)(ws - (char*)d_ws) & 15)) & 15;   // align 16
    uchar_t* p1f = (uchar_t*)ws;                       ws += NH * sizeof(uchar_t);
    uchar_t* p2f = (uchar_t*)ws;                       ws += NO * sizeof(uchar_t);

    const size_t need = (size_t)(ws - (char*)d_ws);
    if (ws_size < need) return;

    // K0: pack weights | zero quarter cursors      (input-only)
    k0_kernel<<<PACK_BLKS + 1, 256, 0, stream>>>(W1l, W1r, W2l, W2r, wpack, gcur);
    // K1: scatter (first) | mm1                    (reads only K0 outputs/inputs)
    k1_kernel<<<MM1_BLKS + EBLKS, 256, 0, stream>>>(
        x, wpack, p1f, t1b, src, dst, gcur, ebuf);
    // Fused fill + agg1 + mm2 (quarter blocks; csr built from own run in regs)
    l2f_kernel<<<L2F_BLKS, 256, 0, stream>>>(
        ebuf, gcur, cnt, row_ptr, csr, p1f, t1b, b1, wpack, p2f, t2b);
    // Final aggregation
    agg2_kernel<<<MM1_BLKS, 256, 0, stream>>>(
        p2f, t2b, b2, row_ptr, cnt, csr, out);
}